// Round 1
// baseline (519.826 us; speedup 1.0000x reference)
//
#include <hip/hip_runtime.h>

#define NBLK 24
#define BATCH 256
#define CCH 32
#define TQ 256
#define TQO 257
#define NCOMP 128         // compute workgroups (2 batches each; wave 0 computes, all 4 waves stage)
#define BPG 2
#define NCOPY 3072        // copy workgroups; 4 waves each; 16 rows/wave
#define ROWS (NBLK*BATCH*CCH)

typedef float f4a4  __attribute__((ext_vector_type(4), aligned(4)));
typedef float f4a16 __attribute__((ext_vector_type(4)));

__global__ __launch_bounds__(256) void w2w_kernel(
    const float* __restrict__ qin,
    const float* __restrict__ x,
    const float* __restrict__ num,
    const int*   __restrict__ cat,
    const float* __restrict__ emb,
    const float* __restrict__ W_in,  const float* __restrict__ b_in,
    const float* __restrict__ W_conv,const float* __restrict__ b_conv,
    const float* __restrict__ W_res, const float* __restrict__ b_res,
    const float* __restrict__ W_skip,const float* __restrict__ b_skip,
    const float* __restrict__ W_o1,  const float* __restrict__ b_o1,
    const float* __restrict__ W_o2,  const float* __restrict__ b_o2,
    float* __restrict__ out, float* __restrict__ qout)
{
    __shared__ __align__(16) float smem[11264];
    const int tid = threadIdx.x;

    if (blockIdx.x >= NCOMP) {
        // ---- bulk copy: qout[r][0:256] = qin[r][0:256], 16B-ALIGNED stores ----
        const int wid  = (blockIdx.x - NCOMP) * 4 + (tid >> 6);
        const int lane = tid & 63;
        size_t r = (size_t)wid * 16;
        for (int rr = 0; rr < 16; ++rr, ++r) {
            const size_t sb = r * TQ, db = r * TQO;
            const int a = (4 - ((int)r & 3)) & 3;        // head so dst f4s are aligned
            if (lane < 63) {
                f4a4 v = *(const f4a4*)(qin + sb + a + 4 * lane);   // align-4 load
                *(f4a16*)(qout + db + a + 4 * lane) = v;            // aligned store
            } else {
                #pragma unroll
                for (int e = 0; e < 4; ++e) {
                    const int f = (e < a) ? e : e + 252;
                    qout[db + f] = qin[sb + f];
                }
            }
        }
        return;
    }

    // ------------- compute: 2 batches/WG (wave 0), 32 lanes/batch -------------
    float* s_wc = smem;            // [0,4096)   W_conv[i]: row m(0..63) x 64
    float* s_wr = smem + 4096;     // [4096,5120) row j x 32
    float* s_ws = smem + 5120;     // [5120,6144)
    float* s_wo = smem + 6144;     // [6144,10240) row m(0..127) x 32 (slice cols i*32..)
    float* s_tc = smem + 10240;    // 2 x 64  (interleaved tap,cur)
    float* s_g  = smem + 10752;    // 2 x 32
    float* s_sk = smem + 11008;    // 2 x 32

    const bool comp = (tid < 64);          // wave 0 computes; waves 1-3 only stage weights
    const int sub = tid >> 5;              // batch-within-WG (valid for comp lanes: 0..1)
    const int j   = tid & 31;
    const int sw  = j & 7;
    const int b   = blockIdx.x * BPG + sub;   // only dereferenced when comp

    // prologue: cur = W_in @ [x,num,emb] + b_in
    float cur = 0.f;
    if (comp) {
        float acc = b_in[j];
        acc = fmaf(W_in[j * 25 + 0], x[b], acc);
        #pragma unroll
        for (int k = 0; k < 8; ++k) acc = fmaf(W_in[j * 25 + 1 + k], num[b * 8 + k], acc);
        const int ci = cat[b];
        #pragma unroll
        for (int k = 0; k < 16; ++k) acc = fmaf(W_in[j * 25 + 9 + k], emb[ci * 16 + k], acc);
        cur = acc;
    }

    float h0 = 0.f, h1 = 0.f, h2 = 0.f, h3 = 0.f;
    f4a16 rg[10];

    // cooperative weight staging: all 256 threads, all LDS-linear
    auto issue = [&](int i) {
        const float* pc = W_conv + (size_t)i * 4096;
        #pragma unroll
        for (int k = 0; k < 4; ++k) rg[k] = *(const f4a16*)(pc + (size_t)(tid + 256 * k) * 4);
        rg[4] = *(const f4a16*)(W_res  + (size_t)i * 1024 + tid * 4);
        rg[5] = *(const f4a16*)(W_skip + (size_t)i * 1024 + tid * 4);
        #pragma unroll
        for (int k = 0; k < 4; ++k) {
            const int fi = tid + 256 * k;              // f4 index 0..1023
            const int m = fi >> 3, p = fi & 7;
            rg[6 + k] = *(const f4a16*)(W_o1 + (size_t)m * 768 + (size_t)i * 32 + p * 4);
        }
    };
    auto commit = [&]() {
        #pragma unroll
        for (int k = 0; k < 4; ++k) *(f4a16*)(s_wc + (tid + 256 * k) * 4) = rg[k];
        *(f4a16*)(s_wr + tid * 4) = rg[4];
        *(f4a16*)(s_ws + tid * 4) = rg[5];
        #pragma unroll
        for (int k = 0; k < 4; ++k) *(f4a16*)(s_wo + (tid + 256 * k) * 4) = rg[6 + k];
    };

    // stage iter 0 + initial tap/cur
    issue(0);
    if (comp) {
        const float t0 = qin[((size_t)b * CCH + j) * TQ + (TQ - 1)];   // i=0, d=1
        s_tc[sub * 64 + 2 * j]     = t0;
        s_tc[sub * 64 + 2 * j + 1] = cur;
    }
    commit();
    __syncthreads();

    for (int i = 0; i < NBLK; ++i) {
        if (i + 1 < NBLK) issue(i + 1);

        if (comp) {
            float tap_nxt = 0.f;
            if (i + 1 < NBLK) {
                const int d = 1 << ((i + 1) & 7);
                tap_nxt = qin[((size_t)((i + 1) * BATCH + b) * CCH + j) * TQ + (TQ - d)];
            }
            const float bc0 = b_conv[i * 64 + j];
            const float bc1 = b_conv[i * 64 + 32 + j];
            const float brj = b_res[i * 32 + j];
            const float bsj = b_skip[i * 32 + j];

            // ---- z = Wc0*tap + Wc1*cur + b  (vector LDS, XOR-swizzled k order) ----
            const f4a16* wr0 = (const f4a16*)(s_wc) + j * 16;
            const f4a16* wr1 = (const f4a16*)(s_wc) + (32 + j) * 16;
            const f4a16* tcv = (const f4a16*)(s_tc) + sub * 16;
            float z0a = 0.f, z0b = 0.f, z1a = 0.f, z1b = 0.f;
            #pragma unroll
            for (int t = 0; t < 16; ++t) {
                const int k = (t & 8) | ((t ^ sw) & 7);
                const f4a16 w0 = wr0[k], w1 = wr1[k], dv = tcv[k];
                z0a = fmaf(w0.x, dv.x, z0a); z0b = fmaf(w0.y, dv.y, z0b);
                z0a = fmaf(w0.z, dv.z, z0a); z0b = fmaf(w0.w, dv.w, z0b);
                z1a = fmaf(w1.x, dv.x, z1a); z1b = fmaf(w1.y, dv.y, z1b);
                z1a = fmaf(w1.z, dv.z, z1a); z1b = fmaf(w1.w, dv.w, z1b);
            }
            const float z0 = z0a + z0b + bc0;
            const float z1 = z1a + z1b + bc1;
            const float g  = tanhf(z0) * (1.f / (1.f + __expf(-z1)));

            // append tap1 (= old cur) into new queue column 256
            qout[((size_t)(i * BATCH + b) * CCH + j) * TQO + TQ] = cur;

            s_g[sub * 32 + j] = g;
            __builtin_amdgcn_wave_barrier();   // comms are wave-internal; LDS is in-order per wave

            // ---- skip & residual ----
            const f4a16* gv  = (const f4a16*)(s_g)  + sub * 8;
            const f4a16* wsv = (const f4a16*)(s_ws) + j * 8;
            const f4a16* wrv = (const f4a16*)(s_wr) + j * 8;
            float ska = bsj, skb = 0.f, cna = brj + cur, cnb = 0.f;
            #pragma unroll
            for (int t = 0; t < 8; ++t) {
                const int k = (t ^ sw) & 7;
                const f4a16 gk = gv[k], wv = wsv[k], rv = wrv[k];
                ska = fmaf(gk.x, wv.x, ska); skb = fmaf(gk.y, wv.y, skb);
                ska = fmaf(gk.z, wv.z, ska); skb = fmaf(gk.w, wv.w, skb);
                cna = fmaf(gk.x, rv.x, cna); cnb = fmaf(gk.y, rv.y, cnb);
                cna = fmaf(gk.z, rv.z, cna); cnb = fmaf(gk.w, rv.w, cnb);
            }
            const float skr = fmaxf(ska + skb, 0.f);
            cur = cna + cnb;

            s_sk[sub * 32 + j] = skr;
            if (i + 1 < NBLK) {   // next iter's tap/cur (read only after the barriers below)
                s_tc[sub * 64 + 2 * j]     = tap_nxt;
                s_tc[sub * 64 + 2 * j + 1] = cur;
            }
            __builtin_amdgcn_wave_barrier();

            // ---- fold skips into h[128] ----
            const f4a16* skv = (const f4a16*)(s_sk) + sub * 8;
            const f4a16* o0 = (const f4a16*)(s_wo) + j * 8;
            const f4a16* o1 = (const f4a16*)(s_wo) + (32 + j) * 8;
            const f4a16* o2 = (const f4a16*)(s_wo) + (64 + j) * 8;
            const f4a16* o3 = (const f4a16*)(s_wo) + (96 + j) * 8;
            #pragma unroll
            for (int t = 0; t < 8; ++t) {
                const int k = (t ^ sw) & 7;
                const f4a16 rv = skv[k];
                const f4a16 a0 = o0[k], a1 = o1[k], a2 = o2[k], a3 = o3[k];
                h0 = fmaf(rv.x, a0.x, h0); h0 = fmaf(rv.y, a0.y, h0);
                h0 = fmaf(rv.z, a0.z, h0); h0 = fmaf(rv.w, a0.w, h0);
                h1 = fmaf(rv.x, a1.x, h1); h1 = fmaf(rv.y, a1.y, h1);
                h1 = fmaf(rv.z, a1.z, h1); h1 = fmaf(rv.w, a1.w, h1);
                h2 = fmaf(rv.x, a2.x, h2); h2 = fmaf(rv.y, a2.y, h2);
                h2 = fmaf(rv.z, a2.z, h2); h2 = fmaf(rv.w, a2.w, h2);
                h3 = fmaf(rv.x, a3.x, h3); h3 = fmaf(rv.y, a3.y, h3);
                h3 = fmaf(rv.z, a3.z, h3); h3 = fmaf(rv.w, a3.w, h3);
            }
        }

        __syncthreads();                 // all reads of weights(i) done
        if (i + 1 < NBLK) commit();      // store weights(i+1)
        __syncthreads();                 // staging visible
    }

    // ---- final MLP + reduce ----
    if (comp) {
        float p = 0.f;
        p = fmaf(fmaxf(h0 + b_o1[j],      0.f), W_o2[j],      p);
        p = fmaf(fmaxf(h1 + b_o1[j + 32], 0.f), W_o2[j + 32], p);
        p = fmaf(fmaxf(h2 + b_o1[j + 64], 0.f), W_o2[j + 64], p);
        p = fmaf(fmaxf(h3 + b_o1[j + 96], 0.f), W_o2[j + 96], p);
        #pragma unroll
        for (int m = 16; m >= 1; m >>= 1) p += __shfl_xor(p, m);
        if (j == 0) out[b] = p + b_o2[0];
    }
}

extern "C" void kernel_launch(void* const* d_in, const int* in_sizes, int n_in,
                              void* d_out, int out_size, void* d_ws, size_t ws_size,
                              hipStream_t stream) {
    const float* qin    = (const float*)d_in[0];
    const float* x      = (const float*)d_in[1];
    const float* num    = (const float*)d_in[2];
    const int*   cat    = (const int*)  d_in[3];
    const float* emb    = (const float*)d_in[4];
    const float* W_in   = (const float*)d_in[5];
    const float* b_in   = (const float*)d_in[6];
    const float* W_conv = (const float*)d_in[7];
    const float* b_conv = (const float*)d_in[8];
    const float* W_res  = (const float*)d_in[9];
    const float* b_res  = (const float*)d_in[10];
    const float* W_skip = (const float*)d_in[11];
    const float* b_skip = (const float*)d_in[12];
    const float* W_o1   = (const float*)d_in[13];
    const float* b_o1   = (const float*)d_in[14];
    const float* W_o2   = (const float*)d_in[15];
    const float* b_o2   = (const float*)d_in[16];

    float* out  = (float*)d_out;
    float* qout = (float*)d_out + BATCH;

    dim3 grid(NCOMP + NCOPY), block(256);
    hipLaunchKernelGGL(w2w_kernel, grid, block, 0, stream,
                       qin, x, num, cat, emb, W_in, b_in, W_conv, b_conv,
                       W_res, b_res, W_skip, b_skip, W_o1, b_o1, W_o2, b_o2,
                       out, qout);
}